// Round 13
// baseline (435.764 us; speedup 1.0000x reference)
//
#include <hip/hip_runtime.h>

// ---------------------------------------------------------------------------
// GraphEncoder round 13:
//  - gathers widened: aggregate256 = 4 edges/instr (16 lanes x uint4/edge),
//    aggregate128 = 8 edges/instr -> half/quarter the VMEM instructions at
//    the same cache-line count (the concurrency floor).
//  - scatter fused into convert_all (disjoint ranges, both post-scanC).
//  - wgemm / CSR scan / pool / LN unchanged.
// ---------------------------------------------------------------------------

typedef __attribute__((ext_vector_type(8))) short short8;
typedef __attribute__((ext_vector_type(4))) float f32x4;
typedef __attribute__((ext_vector_type(2))) float f32x2;

__device__ __forceinline__ float bf2f(unsigned short s) {
    union { unsigned u; float f; } v;
    v.u = ((unsigned)s) << 16;
    return v.f;
}
__device__ __forceinline__ unsigned short f2bf(float f) {
    union { float f; unsigned u; } v;
    v.f = f;
    unsigned r = (v.u + 0x7FFFu + ((v.u >> 16) & 1u)) >> 16;
    return (unsigned short)r;
}

// accumulate 16 fp8 values (uint4) into acc[0..16)
__device__ __forceinline__ void acc16_fp8(uint4 v, float* acc) {
    unsigned int w[4] = {v.x, v.y, v.z, v.w};
    #pragma unroll
    for (int d = 0; d < 4; d++) {
        f32x2 lo = __builtin_amdgcn_cvt_pk_f32_fp8(w[d], false);
        f32x2 hi = __builtin_amdgcn_cvt_pk_f32_fp8(w[d], true);
        acc[d * 4 + 0] += lo[0]; acc[d * 4 + 1] += lo[1];
        acc[d * 4 + 2] += hi[0]; acc[d * 4 + 3] += hi[1];
    }
}

// ---------------------------- CSR build ------------------------------------

__global__ void count_kernel(const int* __restrict__ dst, int E, int* __restrict__ cnt,
                             int* __restrict__ rank) {
    int e = blockIdx.x * blockDim.x + threadIdx.x;
    if (e < E) rank[e] = atomicAdd(&cnt[dst[e]], 1);
}

__global__ void scanA(const int* __restrict__ cnt, int n, int* __restrict__ bsum,
                      float* __restrict__ dinv) {
    int tid = threadIdx.x, lane = tid & 63, w = tid >> 6;
    int i = blockIdx.x * 512 + tid;
    int v = (i < n) ? cnt[i] : 0;
    if (i < n) dinv[i] = rsqrtf((float)v + 1.0f);
    int s = v;
    #pragma unroll
    for (int off = 1; off < 64; off <<= 1) s += __shfl_xor(s, off);
    __shared__ int ws[8];
    if (lane == 0) ws[w] = s;
    __syncthreads();
    if (tid == 0) {
        int t = 0;
        #pragma unroll
        for (int j = 0; j < 8; j++) t += ws[j];
        bsum[blockIdx.x] = t;
    }
}

__global__ void scanC(const int* __restrict__ cnt, int n, const int* __restrict__ bsum,
                      int E, int* __restrict__ row_ptr) {
    int tid = threadIdx.x, lane = tid & 63, w = tid >> 6;
    int i = blockIdx.x * 512 + tid;
    __shared__ int s_boff;
    if (tid < 64) {
        int acc = 0;
        for (int b = tid; b < blockIdx.x; b += 64) acc += bsum[b];
        #pragma unroll
        for (int off = 1; off < 64; off <<= 1) acc += __shfl_xor(acc, off);
        if (tid == 0) s_boff = acc;
    }
    int v = (i < n) ? cnt[i] : 0;
    int incl = v;
    #pragma unroll
    for (int off = 1; off < 64; off <<= 1) {
        int t = __shfl_up(incl, off);
        if (lane >= off) incl += t;
    }
    __shared__ int ws[8];
    if (lane == 63) ws[w] = incl;
    __syncthreads();
    int woff = 0;
    for (int j = 0; j < w; j++) woff += ws[j];
    if (i < n) row_ptr[i] = s_boff + woff + incl - v;
    if (blockIdx.x == 0 && tid == 0) row_ptr[n] = E;
}

// ---------------------------- fused scatter + conversions ------------------
// [0, E):                scatter csr[row_ptr[dst]+rank] = src
// [E, E+n4):             x̂ = dinv*x -> fp8 shadow
// [E+n4, E+n4+tot):      weight transpose W[K,N] fp32 -> Wt[N,K] bf16
// tail (640):            zero fp8 dummy rows

__global__ void convert_all(const int* __restrict__ src, const int* __restrict__ dst,
                            const int* __restrict__ row_ptr, const int* __restrict__ rank,
                            int* __restrict__ csr, int E,
                            const float* __restrict__ x, const float* __restrict__ dinv,
                            unsigned char* __restrict__ xf8, int n4,
                            const float* __restrict__ W1, const float* __restrict__ W2,
                            const float* __restrict__ W3, const float* __restrict__ P1,
                            const float* __restrict__ P2,
                            unsigned short* __restrict__ Wt1, unsigned short* __restrict__ Wt2,
                            unsigned short* __restrict__ Wt3, unsigned short* __restrict__ Pt1,
                            unsigned short* __restrict__ Pt2,
                            int F_IN, int H, int D,
                            unsigned char* __restrict__ zx,
                            unsigned char* __restrict__ z1,
                            unsigned char* __restrict__ z2) {
    int gidx = blockIdx.x * blockDim.x + threadIdx.x;
    if (gidx < E) {
        csr[row_ptr[dst[gidx]] + rank[gidx]] = src[gidx];
        return;
    }
    int idx = gidx - E;
    if (idx < n4) {
        float di = dinv[idx >> 5];
        float4 v = ((const float4*)x)[idx];
        unsigned int p = 0;
        p = __builtin_amdgcn_cvt_pk_fp8_f32(di * v.x, di * v.y, p, false);
        p = __builtin_amdgcn_cvt_pk_fp8_f32(di * v.z, di * v.w, p, true);
        ((unsigned int*)xf8)[idx] = p;
        return;
    }
    int t = idx - n4;
    int n1 = F_IN * H, n2 = H * H, n5 = H * D;
    const float* W; unsigned short* O; int N;
    if (t < n1)              { W = W1; O = Wt1; N = H; }
    else if ((t -= n1) < n2) { W = W2; O = Wt2; N = H; }
    else if ((t -= n2) < n2) { W = W3; O = Wt3; N = H; }
    else if ((t -= n2) < n2) { W = P1; O = Pt1; N = H; }
    else if ((t -= n2) < n5) { W = P2; O = Pt2; N = D; }
    else {
        t -= n5;
        if (t < 128) zx[t] = 0;
        else if (t < 384) z1[t - 128] = 0;
        else if (t < 640) z2[t - 384] = 0;
        return;
    }
    int k = t / N, n = t - k * N;
    int K = (W == W1) ? F_IN : H;
    O[(size_t)n * K + k] = f2bf(W[t]);
}

// ---------------------------- aggregation (fp8 gathers) --------------------
// t[node] = self + sum_e h[src_e]; fp8 256B rows; 16 lanes x uint4 per edge
// -> 4 edges per instruction; 8-deep unroll = 32 edges in flight.

__launch_bounds__(256)
__global__ void aggregate256(const unsigned char* __restrict__ hf8,
                             const int* __restrict__ row_ptr,
                             const int* __restrict__ csr,
                             unsigned short* __restrict__ out, int n, int zrow) {
    int node = blockIdx.x * 4 + (threadIdx.x >> 6);
    int lane = threadIdx.x & 63;
    if (node >= n) return;
    int qtr = lane >> 4;           // edge slot 0..3
    int cl = lane & 15;            // 16-byte chunk (16 fp8 cols)
    float acc[16];
    #pragma unroll
    for (int c = 0; c < 16; c++) acc[c] = 0.f;
    if (qtr == 0) {
        uint4 sv = *(const uint4*)(hf8 + (size_t)node * 256 + cl * 16);
        acc16_fp8(sv, acc);
    }
    int beg = row_ptr[node], end = row_ptr[node + 1];
    for (int base = beg; base < end; base += 64) {
        int k = base + lane;
        int mi = (k < end) ? csr[k] : zrow;
        int cnt = min(64, end - base);
        for (int j = 0; j < cnt; j += 32) {
            int idx[8]; uint4 vv[8];
            #pragma unroll
            for (int u = 0; u < 8; u++) idx[u] = __shfl(mi, j + 4 * u + qtr);
            #pragma unroll
            for (int u = 0; u < 8; u++) vv[u] = *(const uint4*)(hf8 + (size_t)idx[u] * 256 + cl * 16);
            #pragma unroll
            for (int u = 0; u < 8; u++) acc16_fp8(vv[u], acc);
        }
    }
    #pragma unroll
    for (int c = 0; c < 16; c++) {
        acc[c] += __shfl_xor(acc[c], 16);
        acc[c] += __shfl_xor(acc[c], 32);
    }
    if (qtr == 0) {
        short8 o0, o1;
        #pragma unroll
        for (int c = 0; c < 8; c++) { o0[c] = (short)f2bf(acc[c]); o1[c] = (short)f2bf(acc[c + 8]); }
        unsigned short* op = out + (size_t)node * 256 + cl * 16;
        *(short8*)op = o0;
        *(short8*)(op + 8) = o1;
    }
}

// 128-col fp8 rows (128B): 8 lanes x uint4 per edge -> 8 edges/instr.
__launch_bounds__(256)
__global__ void aggregate128(const unsigned char* __restrict__ hf8,
                             const int* __restrict__ row_ptr,
                             const int* __restrict__ csr,
                             unsigned short* __restrict__ out, int n, int zrow) {
    int node = blockIdx.x * 4 + (threadIdx.x >> 6);
    int lane = threadIdx.x & 63;
    if (node >= n) return;
    int egt = lane >> 3;           // edge slot 0..7
    int cl = lane & 7;             // 16-byte chunk
    float acc[16];
    #pragma unroll
    for (int c = 0; c < 16; c++) acc[c] = 0.f;
    if (egt == 0) {
        uint4 sv = *(const uint4*)(hf8 + (size_t)node * 128 + cl * 16);
        acc16_fp8(sv, acc);
    }
    int beg = row_ptr[node], end = row_ptr[node + 1];
    for (int base = beg; base < end; base += 64) {
        int k = base + lane;
        int mi = (k < end) ? csr[k] : zrow;
        int cnt = min(64, end - base);
        for (int j = 0; j < cnt; j += 64) {
            int idx[8]; uint4 vv[8];
            #pragma unroll
            for (int u = 0; u < 8; u++) idx[u] = __shfl(mi, j + 8 * u + egt);
            #pragma unroll
            for (int u = 0; u < 8; u++) vv[u] = *(const uint4*)(hf8 + (size_t)idx[u] * 128 + cl * 16);
            #pragma unroll
            for (int u = 0; u < 8; u++) acc16_fp8(vv[u], acc);
        }
    }
    #pragma unroll
    for (int c = 0; c < 16; c++) {
        acc[c] += __shfl_xor(acc[c], 8);
        acc[c] += __shfl_xor(acc[c], 16);
        acc[c] += __shfl_xor(acc[c], 32);
    }
    if (egt == 0) {
        short8 o0, o1;
        #pragma unroll
        for (int c = 0; c < 8; c++) { o0[c] = (short)f2bf(acc[c]); o1[c] = (short)f2bf(acc[c + 8]); }
        unsigned short* op = out + (size_t)node * 128 + cl * 16;
        *(short8*)op = o0;
        *(short8*)(op + 8) = o1;
    }
}

// ---------------------------- wgemm ----------------------------------------
// C = epi(A[M,K] @ Bt[N,K]^T). 256-thr blocks = 4 waves x 32 rows (128 rows).
// A frags in registers; per 64-col tile B staged to LDS; LDS-transpose
// epilogue -> coalesced vectorized residual loads + stores.
// SCALE: 0 plain; 1: v=relu(di*acc+b)[+res/di], store di*v; 2: ...store v.
// FP8O: also store v as fp8 shadow (gather copy for the next aggregate).

template<int K, int RELU, int RES, int OUTF32, int SCALE, int FP8O>
__launch_bounds__(256)
__global__ void wgemm(const unsigned short* __restrict__ A,
                      const unsigned short* __restrict__ Bt,
                      const float* __restrict__ bias,
                      const unsigned short* __restrict__ residual,
                      const float* __restrict__ dinv,
                      void* __restrict__ Cout,
                      unsigned char* __restrict__ f8out,
                      int M, int N, int ntiles) {
    constexpr int KK = K / 32;
    constexpr int S = K + 8;
    constexpr int CS = 65;
    constexpr int BSZ = 64 * S * 2;
    constexpr int CSZ = 128 * CS * 4;
    constexpr int SM = BSZ > CSZ ? BSZ : CSZ;
    __shared__ __align__(16) char smraw[SM];
    unsigned short* Bs = (unsigned short*)smraw;
    float* Cs = (float*)smraw;
    constexpr int CPR = K / 8;

    int tid = threadIdx.x;
    int wave = tid >> 6, lane = tid & 63;
    int r = lane & 15, q = lane >> 4;
    int mr = blockIdx.y * 128 + wave * 32;
    int nbase = blockIdx.x * ntiles * 64;

    short8 a[2][KK];
    #pragma unroll
    for (int mi = 0; mi < 2; mi++) {
        int arow = mr + mi * 16 + r;
        bool ok = arow < M;
        const unsigned short* ap = A + (size_t)(ok ? arow : 0) * K;
        #pragma unroll
        for (int kk = 0; kk < KK; kk++) {
            short8 v = *(const short8*)(ap + kk * 32 + q * 8);
            if (!ok) v = (short8){0, 0, 0, 0, 0, 0, 0, 0};
            a[mi][kk] = v;
        }
    }

    for (int t = 0; t < ntiles; t++) {
        int n0 = nbase + t * 64;
        if (t > 0) __syncthreads();
        #pragma unroll
        for (int pass = 0; pass < 64 * CPR / 256; pass++) {
            int f = pass * 256 + tid;
            int row = f / CPR, ch = f % CPR;
            *(short8*)&Bs[row * S + ch * 8] =
                *(const short8*)(Bt + (size_t)(n0 + row) * K + ch * 8);
        }
        __syncthreads();

        f32x4 acc[2][4];
        #pragma unroll
        for (int mi = 0; mi < 2; mi++)
            #pragma unroll
            for (int j = 0; j < 4; j++) acc[mi][j] = (f32x4){0.f, 0.f, 0.f, 0.f};

        #pragma unroll
        for (int kk = 0; kk < KK; kk++) {
            short8 b[4];
            #pragma unroll
            for (int j = 0; j < 4; j++)
                b[j] = *(short8*)&Bs[(j * 16 + r) * S + kk * 32 + q * 8];
            #pragma unroll
            for (int mi = 0; mi < 2; mi++)
                #pragma unroll
                for (int j = 0; j < 4; j++)
                    acc[mi][j] = __builtin_amdgcn_mfma_f32_16x16x32_bf16(a[mi][kk], b[j], acc[mi][j], 0, 0, 0);
        }

        __syncthreads();
        #pragma unroll
        for (int mi = 0; mi < 2; mi++)
            #pragma unroll
            for (int j = 0; j < 4; j++)
                #pragma unroll
                for (int p = 0; p < 4; p++)
                    Cs[(wave * 32 + mi * 16 + q * 4 + p) * CS + j * 16 + r] = acc[mi][j][p];
        __syncthreads();

        int row = tid >> 1;
        int halfc = (tid & 1) * 32;
        int grow = blockIdx.y * 128 + row;
        if (grow < M) {
            float vals[32];
            #pragma unroll
            for (int c = 0; c < 8; c++)
                *(f32x4*)&vals[c * 4] = *(f32x4*)&Cs[row * CS + halfc + c * 4];
            float di = 1.f, rdi = 1.f;
            if (SCALE) { di = dinv[grow]; if (RES) rdi = 1.f / di; }
            float bb[32];
            #pragma unroll
            for (int c = 0; c < 8; c++)
                *(f32x4*)&bb[c * 4] = *(const f32x4*)&bias[n0 + halfc + c * 4];
            short8 rv[4];
            if (RES) {
                #pragma unroll
                for (int c = 0; c < 4; c++)
                    rv[c] = *(const short8*)(residual + (size_t)grow * N + n0 + halfc + c * 8);
            }
            #pragma unroll
            for (int c = 0; c < 32; c++) {
                float v = (SCALE ? di * vals[c] : vals[c]) + bb[c];
                if (RELU) v = fmaxf(v, 0.f);
                if (RES) v += bf2f((unsigned short)rv[c / 8][c % 8]) * rdi;
                if (SCALE == 1) v *= di;
                vals[c] = v;
            }
            if (OUTF32) {
                float* cp = (float*)Cout + (size_t)grow * N + n0 + halfc;
                #pragma unroll
                for (int c = 0; c < 8; c++) *(f32x4*)&cp[c * 4] = *(f32x4*)&vals[c * 4];
            } else {
                unsigned short* cp = (unsigned short*)Cout + (size_t)grow * N + n0 + halfc;
                #pragma unroll
                for (int c = 0; c < 4; c++) {
                    short8 o;
                    #pragma unroll
                    for (int u = 0; u < 8; u++) o[u] = (short)f2bf(vals[c * 8 + u]);
                    *(short8*)&cp[c * 8] = o;
                }
            }
            if (FP8O) {
                unsigned int w[8];
                #pragma unroll
                for (int c = 0; c < 8; c++) {
                    unsigned int p = 0;
                    p = __builtin_amdgcn_cvt_pk_fp8_f32(vals[c * 4 + 0], vals[c * 4 + 1], p, false);
                    p = __builtin_amdgcn_cvt_pk_fp8_f32(vals[c * 4 + 2], vals[c * 4 + 3], p, true);
                    w[c] = p;
                }
                unsigned char* fp = f8out + (size_t)grow * N + n0 + halfc;
                *(uint4*)(fp) = make_uint4(w[0], w[1], w[2], w[3]);
                *(uint4*)(fp + 16) = make_uint4(w[4], w[5], w[6], w[7]);
            }
        }
    }
}

// ---------------------------- pool / LN ------------------------------------

__launch_bounds__(256)
__global__ void pool_kernel(const unsigned short* __restrict__ h, const int* __restrict__ batch,
                            unsigned short* __restrict__ g0, int n, int G) {
    int g = blockIdx.x * 4 + (threadIdx.x >> 6);
    int lane = threadIdx.x & 63;
    if (g >= G) return;
    int lo = 0, hi = 0;
    if (lane == 0) {
        int a = 0, b = n;
        while (a < b) { int m = (a + b) >> 1; if (batch[m] < g) a = m + 1; else b = m; }
        lo = a;
        int a2 = a, b2 = n;
        while (a2 < b2) { int m = (a2 + b2) >> 1; if (batch[m] < g + 1) a2 = m + 1; else b2 = m; }
        hi = a2;
    }
    lo = __shfl(lo, 0); hi = __shfl(hi, 0);
    float a0 = 0.f, a1 = 0.f, a2 = 0.f, a3 = 0.f;
    for (int i = lo; i < hi; i++) {
        ushort4 v = *(const ushort4*)(h + (size_t)i * 256 + lane * 4);
        a0 += bf2f(v.x); a1 += bf2f(v.y); a2 += bf2f(v.z); a3 += bf2f(v.w);
    }
    float inv = 1.0f / fmaxf((float)(hi - lo), 1.0f);
    ushort4 o;
    o.x = f2bf(a0 * inv); o.y = f2bf(a1 * inv); o.z = f2bf(a2 * inv); o.w = f2bf(a3 * inv);
    *(ushort4*)(g0 + (size_t)g * 256 + lane * 4) = o;
}

__launch_bounds__(256)
__global__ void ln_kernel(const float* __restrict__ g2, const float* __restrict__ gamma,
                          const float* __restrict__ beta, float* __restrict__ out, int rows) {
    int row = blockIdx.x * 4 + (threadIdx.x >> 6);
    int lane = threadIdx.x & 63;
    if (row >= rows) return;
    const float* r = g2 + (size_t)row * 768;
    float v[12];
    float s = 0.f, s2 = 0.f;
    #pragma unroll
    for (int j = 0; j < 12; j++) {
        v[j] = r[lane + 64 * j];
        s += v[j];
        s2 += v[j] * v[j];
    }
    #pragma unroll
    for (int off = 32; off > 0; off >>= 1) {
        s += __shfl_down(s, off);
        s2 += __shfl_down(s2, off);
    }
    s = __shfl(s, 0);
    s2 = __shfl(s2, 0);
    float mu = s * (1.0f / 768.0f);
    float var = s2 * (1.0f / 768.0f) - mu * mu;
    float inv = rsqrtf(var + 1e-5f);
    #pragma unroll
    for (int j = 0; j < 12; j++) {
        int c = lane + 64 * j;
        out[(size_t)row * 768 + c] = (v[j] - mu) * inv * gamma[c] + beta[c];
    }
}

// ---------------------------------------------------------------------------

extern "C" void kernel_launch(void* const* d_in, const int* in_sizes, int n_in,
                              void* d_out, int out_size, void* d_ws, size_t ws_size,
                              hipStream_t stream) {
    const float* x    = (const float*)d_in[0];
    const int* eidx   = (const int*)d_in[1];
    const int* batch  = (const int*)d_in[2];
    const float* W1   = (const float*)d_in[3];
    const float* b1   = (const float*)d_in[4];
    const float* W2   = (const float*)d_in[5];
    const float* b2   = (const float*)d_in[6];
    const float* W3   = (const float*)d_in[7];
    const float* b3   = (const float*)d_in[8];
    const float* P1   = (const float*)d_in[9];
    const float* pb1  = (const float*)d_in[10];
    const float* P2   = (const float*)d_in[11];
    const float* pb2  = (const float*)d_in[12];
    const float* ln_g = (const float*)d_in[13];
    const float* ln_b = (const float*)d_in[14];
    float* out = (float*)d_out;

    const int N = in_sizes[2];            // 50000
    const int E = in_sizes[1] / 2;        // 800000
    const int F_IN = in_sizes[0] / N;     // 128
    const int H = in_sizes[4];            // 256
    const int D = in_sizes[12];           // 768
    const int G = out_size / D;           // 1024
    const int NPAD = (N + 127) & ~127;
    const int NB = (N + 511) / 512;       // scan blocks (<=128)

    const int* src = eidx;
    const int* dst = eidx + E;

    char* ws = (char*)d_ws;
    size_t off = 0;
    auto alloc = [&](size_t bytes) -> char* {
        char* p = ws + off;
        off = (off + bytes + 255) & ~(size_t)255;
        return p;
    };
    int*   cnt      = (int*)alloc((size_t)NPAD * 4);
    float* dinv     = (float*)alloc((size_t)NPAD * 4);
    int*   row_ptr  = (int*)alloc((size_t)(N + 1) * 4);
    int*   bsum     = (int*)alloc(128 * 4);
    int*   rank     = (int*)alloc((size_t)E * 4);
    int*   csr      = (int*)alloc((size_t)E * 4);
    unsigned char* xf8  = (unsigned char*)alloc((size_t)(N + 1) * F_IN);      // x̂ fp8, +dummy
    unsigned char* h1f8 = (unsigned char*)alloc((size_t)(N + 1) * H);         // ĥ1 fp8, +dummy
    unsigned char* h2f8 = (unsigned char*)alloc((size_t)(N + 1) * H);         // ĥ2 fp8, +dummy
    unsigned short* Wt1 = (unsigned short*)alloc((size_t)F_IN * H * 2);
    unsigned short* Wt2 = (unsigned short*)alloc((size_t)H * H * 2);
    unsigned short* Wt3 = (unsigned short*)alloc((size_t)H * H * 2);
    unsigned short* Pt1 = (unsigned short*)alloc((size_t)H * H * 2);
    unsigned short* Pt2 = (unsigned short*)alloc((size_t)H * D * 2);
    unsigned short* t1  = (unsigned short*)alloc((size_t)N * F_IN * 2);       // Σ x̂ (bf16)
    unsigned short* tA  = (unsigned short*)alloc((size_t)N * H * 2);          // Σ ĥ (bf16)
    unsigned short* hh1 = (unsigned short*)alloc((size_t)N * H * 2);          // ĥ1 bf16 (residual)
    unsigned short* hh2 = (unsigned short*)alloc((size_t)N * H * 2);          // ĥ2 bf16 (residual)
    unsigned short* h3  = (unsigned short*)alloc((size_t)N * H * 2);
    unsigned short* g0b = (unsigned short*)alloc((size_t)G * H * 2);
    unsigned short* g1b = (unsigned short*)alloc((size_t)G * H * 2);
    float* g2 = (float*)alloc((size_t)G * D * 4);
    (void)ws_size; (void)n_in;

    // --- CSR build -----------------------------------------------------------
    hipMemsetAsync(cnt, 0, (size_t)NPAD * 4, stream);
    count_kernel<<<(E + 255) / 256, 256, 0, stream>>>(dst, E, cnt, rank);
    scanA<<<NB, 512, 0, stream>>>(cnt, N, bsum, dinv);
    scanC<<<NB, 512, 0, stream>>>(cnt, N, bsum, E, row_ptr);

    // --- fused scatter + conversions (one launch) ---------------------------
    {
        int n4 = N * F_IN / 4;
        int tot = F_IN * H + 3 * H * H + H * D;
        int total = E + n4 + tot + 640;
        convert_all<<<(total + 255) / 256, 256, 0, stream>>>(
            src, dst, row_ptr, rank, csr, E,
            x, dinv, xf8, n4, W1, W2, W3, P1, P2, Wt1, Wt2, Wt3, Pt1, Pt2, F_IN, H, D,
            xf8 + (size_t)N * F_IN, h1f8 + (size_t)N * H, h2f8 + (size_t)N * H);
    }

    // --- GCN layers (aggregate-first, ĥ-space, fp8 gathers) -----------------
    int agg_grid = (N + 3) / 4;
    int mtiles = (N + 127) / 128;

    // layer 1: t1 = x̂[i] + Σ x̂[src]; ĥ1 = di*relu(di*(t1 W1) + b1)  (+fp8)
    aggregate128<<<agg_grid, 256, 0, stream>>>(xf8, row_ptr, csr, t1, N, N);
    wgemm<128, 1, 0, 0, 1, 1><<<dim3(4, mtiles), 256, 0, stream>>>(t1, Wt1, b1, nullptr, dinv, hh1, h1f8, N, H, 1);

    // layer 2: t2 = ĥ1[i] + Σ ĥ1[src]; ĥ2 = di*(relu(di*(t2 W2)+b2) + ĥ1/di)
    aggregate256<<<agg_grid, 256, 0, stream>>>(h1f8, row_ptr, csr, tA, N, N);
    wgemm<256, 1, 1, 0, 1, 1><<<dim3(4, mtiles), 256, 0, stream>>>(tA, Wt2, b2, hh1, dinv, hh2, h2f8, N, H, 1);

    // layer 3: t3 = ĥ2[i] + Σ ĥ2[src]; h3 = relu(di*(t3 W3)+b3) + ĥ2/di
    aggregate256<<<agg_grid, 256, 0, stream>>>(h2f8, row_ptr, csr, tA, N, N);
    wgemm<256, 1, 1, 0, 2, 0><<<dim3(4, mtiles), 256, 0, stream>>>(tA, Wt3, b3, hh2, dinv, h3, nullptr, N, H, 1);

    // --- pool + MLP + LN -----------------------------------------------------
    pool_kernel<<<(G + 3) / 4, 256, 0, stream>>>(h3, batch, g0b, N, G);
    wgemm<256, 1, 0, 0, 0, 0><<<dim3(4, G / 128), 256, 0, stream>>>(g0b, Pt1, pb1, nullptr, nullptr, g1b, nullptr, G, H, 1);
    wgemm<256, 0, 0, 1, 0, 0><<<dim3(12, G / 128), 256, 0, stream>>>(g1b, Pt2, pb2, nullptr, nullptr, g2, nullptr, G, D, 1);
    ln_kernel<<<G / 4, 256, 0, stream>>>(g2, ln_g, ln_b, out, G);
}

// Round 14
// 371.626 us; speedup vs baseline: 1.1726x; 1.1726x over previous
//
#include <hip/hip_runtime.h>

// ---------------------------------------------------------------------------
// GraphEncoder round 14: revert R13's widened gathers (regression: 64/32-slot
// granularity vs mean degree 16 -> 2-4x dummy gathers; VGPR 32->84 halved
// occupancy). Aggregators restored to R12's measured-optimal shape
// (2 edges/instr @16 slots for 256-col, 4 edges/instr @32 slots for 128-col).
// Kept from R13: fused scatter+convert single dispatch.
// ---------------------------------------------------------------------------

typedef __attribute__((ext_vector_type(8))) short short8;
typedef __attribute__((ext_vector_type(4))) float f32x4;
typedef __attribute__((ext_vector_type(2))) float f32x2;

__device__ __forceinline__ float bf2f(unsigned short s) {
    union { unsigned u; float f; } v;
    v.u = ((unsigned)s) << 16;
    return v.f;
}
__device__ __forceinline__ unsigned short f2bf(float f) {
    union { float f; unsigned u; } v;
    v.f = f;
    unsigned r = (v.u + 0x7FFFu + ((v.u >> 16) & 1u)) >> 16;
    return (unsigned short)r;
}

// accumulate 8 fp8 values (two packed dwords) into acc[0..8)
__device__ __forceinline__ void acc8_fp8(unsigned int lo, unsigned int hi, float* acc) {
    f32x2 p0 = __builtin_amdgcn_cvt_pk_f32_fp8(lo, false);
    f32x2 p1 = __builtin_amdgcn_cvt_pk_f32_fp8(lo, true);
    f32x2 p2 = __builtin_amdgcn_cvt_pk_f32_fp8(hi, false);
    f32x2 p3 = __builtin_amdgcn_cvt_pk_f32_fp8(hi, true);
    acc[0] += p0[0]; acc[1] += p0[1]; acc[2] += p1[0]; acc[3] += p1[1];
    acc[4] += p2[0]; acc[5] += p2[1]; acc[6] += p3[0]; acc[7] += p3[1];
}

// ---------------------------- CSR build ------------------------------------

__global__ void count_kernel(const int* __restrict__ dst, int E, int* __restrict__ cnt,
                             int* __restrict__ rank) {
    int e = blockIdx.x * blockDim.x + threadIdx.x;
    if (e < E) rank[e] = atomicAdd(&cnt[dst[e]], 1);
}

__global__ void scanA(const int* __restrict__ cnt, int n, int* __restrict__ bsum,
                      float* __restrict__ dinv) {
    int tid = threadIdx.x, lane = tid & 63, w = tid >> 6;
    int i = blockIdx.x * 512 + tid;
    int v = (i < n) ? cnt[i] : 0;
    if (i < n) dinv[i] = rsqrtf((float)v + 1.0f);
    int s = v;
    #pragma unroll
    for (int off = 1; off < 64; off <<= 1) s += __shfl_xor(s, off);
    __shared__ int ws[8];
    if (lane == 0) ws[w] = s;
    __syncthreads();
    if (tid == 0) {
        int t = 0;
        #pragma unroll
        for (int j = 0; j < 8; j++) t += ws[j];
        bsum[blockIdx.x] = t;
    }
}

__global__ void scanC(const int* __restrict__ cnt, int n, const int* __restrict__ bsum,
                      int E, int* __restrict__ row_ptr) {
    int tid = threadIdx.x, lane = tid & 63, w = tid >> 6;
    int i = blockIdx.x * 512 + tid;
    __shared__ int s_boff;
    if (tid < 64) {
        int acc = 0;
        for (int b = tid; b < blockIdx.x; b += 64) acc += bsum[b];
        #pragma unroll
        for (int off = 1; off < 64; off <<= 1) acc += __shfl_xor(acc, off);
        if (tid == 0) s_boff = acc;
    }
    int v = (i < n) ? cnt[i] : 0;
    int incl = v;
    #pragma unroll
    for (int off = 1; off < 64; off <<= 1) {
        int t = __shfl_up(incl, off);
        if (lane >= off) incl += t;
    }
    __shared__ int ws[8];
    if (lane == 63) ws[w] = incl;
    __syncthreads();
    int woff = 0;
    for (int j = 0; j < w; j++) woff += ws[j];
    if (i < n) row_ptr[i] = s_boff + woff + incl - v;
    if (blockIdx.x == 0 && tid == 0) row_ptr[n] = E;
}

// ---------------------------- fused scatter + conversions ------------------
// [0, E):           scatter csr[row_ptr[dst]+rank] = src
// [E, E+n4):        x̂ = dinv*x -> fp8 shadow
// [E+n4, E+n4+tot): weight transpose W[K,N] fp32 -> Wt[N,K] bf16
// tail (640):       zero fp8 dummy rows

__global__ void convert_all(const int* __restrict__ src, const int* __restrict__ dst,
                            const int* __restrict__ row_ptr, const int* __restrict__ rank,
                            int* __restrict__ csr, int E,
                            const float* __restrict__ x, const float* __restrict__ dinv,
                            unsigned char* __restrict__ xf8, int n4,
                            const float* __restrict__ W1, const float* __restrict__ W2,
                            const float* __restrict__ W3, const float* __restrict__ P1,
                            const float* __restrict__ P2,
                            unsigned short* __restrict__ Wt1, unsigned short* __restrict__ Wt2,
                            unsigned short* __restrict__ Wt3, unsigned short* __restrict__ Pt1,
                            unsigned short* __restrict__ Pt2,
                            int F_IN, int H, int D,
                            unsigned char* __restrict__ zx,
                            unsigned char* __restrict__ z1,
                            unsigned char* __restrict__ z2) {
    int gidx = blockIdx.x * blockDim.x + threadIdx.x;
    if (gidx < E) {
        csr[row_ptr[dst[gidx]] + rank[gidx]] = src[gidx];
        return;
    }
    int idx = gidx - E;
    if (idx < n4) {
        float di = dinv[idx >> 5];
        float4 v = ((const float4*)x)[idx];
        unsigned int p = 0;
        p = __builtin_amdgcn_cvt_pk_fp8_f32(di * v.x, di * v.y, p, false);
        p = __builtin_amdgcn_cvt_pk_fp8_f32(di * v.z, di * v.w, p, true);
        ((unsigned int*)xf8)[idx] = p;
        return;
    }
    int t = idx - n4;
    int n1 = F_IN * H, n2 = H * H, n5 = H * D;
    const float* W; unsigned short* O; int N;
    if (t < n1)              { W = W1; O = Wt1; N = H; }
    else if ((t -= n1) < n2) { W = W2; O = Wt2; N = H; }
    else if ((t -= n2) < n2) { W = W3; O = Wt3; N = H; }
    else if ((t -= n2) < n2) { W = P1; O = Pt1; N = H; }
    else if ((t -= n2) < n5) { W = P2; O = Pt2; N = D; }
    else {
        t -= n5;
        if (t < 128) zx[t] = 0;
        else if (t < 384) z1[t - 128] = 0;
        else if (t < 640) z2[t - 384] = 0;
        return;
    }
    int k = t / N, n = t - k * N;
    int K = (W == W1) ? F_IN : H;
    O[(size_t)n * K + k] = f2bf(W[t]);
}

// ---------------------------- aggregation (fp8 gathers, R12 shape) ---------
// t[node] = self + sum_e h[src_e]; fp8 rows; dummy row `zrow` pads tails.
// 256-col: half-wave x uint2 per edge (2 edges/instr, 16 slots/iter).

__launch_bounds__(256)
__global__ void aggregate256(const unsigned char* __restrict__ hf8,
                             const int* __restrict__ row_ptr,
                             const int* __restrict__ csr,
                             unsigned short* __restrict__ out, int n, int zrow) {
    int node = blockIdx.x * 4 + (threadIdx.x >> 6);
    int lane = threadIdx.x & 63;
    if (node >= n) return;
    int half = lane >> 5;          // which edge of the pair
    int cl = lane & 31;            // 8-col chunk
    float acc[8] = {0, 0, 0, 0, 0, 0, 0, 0};
    if (half == 0) {
        uint2 sv = *(const uint2*)(hf8 + (size_t)node * 256 + cl * 8);
        acc8_fp8(sv.x, sv.y, acc);
    }
    int beg = row_ptr[node], end = row_ptr[node + 1];
    for (int base = beg; base < end; base += 64) {
        int k = base + lane;
        int mi = (k < end) ? csr[k] : zrow;
        int cnt = min(64, end - base);
        for (int j = 0; j < cnt; j += 16) {
            int idx[8]; uint2 vv[8];
            #pragma unroll
            for (int u = 0; u < 8; u++) idx[u] = __shfl(mi, j + 2 * u + half);
            #pragma unroll
            for (int u = 0; u < 8; u++) vv[u] = *(const uint2*)(hf8 + (size_t)idx[u] * 256 + cl * 8);
            #pragma unroll
            for (int u = 0; u < 8; u++) acc8_fp8(vv[u].x, vv[u].y, acc);
        }
    }
    #pragma unroll
    for (int c = 0; c < 8; c++) acc[c] += __shfl_xor(acc[c], 32);
    if (half == 0) {
        short8 o;
        #pragma unroll
        for (int c = 0; c < 8; c++) o[c] = (short)f2bf(acc[c]);
        *(short8*)(out + (size_t)node * 256 + cl * 8) = o;
    }
}

// 128-col rows: quarter-wave x uint2 per edge (4 edges/instr, 32 slots/iter).
__launch_bounds__(256)
__global__ void aggregate128(const unsigned char* __restrict__ hf8,
                             const int* __restrict__ row_ptr,
                             const int* __restrict__ csr,
                             unsigned short* __restrict__ out, int n, int zrow) {
    int node = blockIdx.x * 4 + (threadIdx.x >> 6);
    int lane = threadIdx.x & 63;
    if (node >= n) return;
    int qtr = lane >> 4;           // which edge of the quad
    int cl = lane & 15;            // 8-col chunk
    float acc[8] = {0, 0, 0, 0, 0, 0, 0, 0};
    if (qtr == 0) {
        uint2 sv = *(const uint2*)(hf8 + (size_t)node * 128 + cl * 8);
        acc8_fp8(sv.x, sv.y, acc);
    }
    int beg = row_ptr[node], end = row_ptr[node + 1];
    for (int base = beg; base < end; base += 64) {
        int k = base + lane;
        int mi = (k < end) ? csr[k] : zrow;
        int cnt = min(64, end - base);
        for (int j = 0; j < cnt; j += 32) {
            int idx[8]; uint2 vv[8];
            #pragma unroll
            for (int u = 0; u < 8; u++) idx[u] = __shfl(mi, j + 4 * u + qtr);
            #pragma unroll
            for (int u = 0; u < 8; u++) vv[u] = *(const uint2*)(hf8 + (size_t)idx[u] * 128 + cl * 8);
            #pragma unroll
            for (int u = 0; u < 8; u++) acc8_fp8(vv[u].x, vv[u].y, acc);
        }
    }
    #pragma unroll
    for (int c = 0; c < 8; c++) {
        acc[c] += __shfl_xor(acc[c], 16);
        acc[c] += __shfl_xor(acc[c], 32);
    }
    if (qtr == 0) {
        short8 o;
        #pragma unroll
        for (int c = 0; c < 8; c++) o[c] = (short)f2bf(acc[c]);
        *(short8*)(out + (size_t)node * 128 + cl * 8) = o;
    }
}

// ---------------------------- wgemm ----------------------------------------
// C = epi(A[M,K] @ Bt[N,K]^T). 256-thr blocks = 4 waves x 32 rows (128 rows).
// A frags in registers; per 64-col tile B staged to LDS; LDS-transpose
// epilogue -> coalesced vectorized residual loads + stores.
// SCALE: 0 plain; 1: v=relu(di*acc+b)[+res/di], store di*v; 2: ...store v.
// FP8O: also store v as fp8 shadow (gather copy for the next aggregate).

template<int K, int RELU, int RES, int OUTF32, int SCALE, int FP8O>
__launch_bounds__(256)
__global__ void wgemm(const unsigned short* __restrict__ A,
                      const unsigned short* __restrict__ Bt,
                      const float* __restrict__ bias,
                      const unsigned short* __restrict__ residual,
                      const float* __restrict__ dinv,
                      void* __restrict__ Cout,
                      unsigned char* __restrict__ f8out,
                      int M, int N, int ntiles) {
    constexpr int KK = K / 32;
    constexpr int S = K + 8;
    constexpr int CS = 65;
    constexpr int BSZ = 64 * S * 2;
    constexpr int CSZ = 128 * CS * 4;
    constexpr int SM = BSZ > CSZ ? BSZ : CSZ;
    __shared__ __align__(16) char smraw[SM];
    unsigned short* Bs = (unsigned short*)smraw;
    float* Cs = (float*)smraw;
    constexpr int CPR = K / 8;

    int tid = threadIdx.x;
    int wave = tid >> 6, lane = tid & 63;
    int r = lane & 15, q = lane >> 4;
    int mr = blockIdx.y * 128 + wave * 32;
    int nbase = blockIdx.x * ntiles * 64;

    short8 a[2][KK];
    #pragma unroll
    for (int mi = 0; mi < 2; mi++) {
        int arow = mr + mi * 16 + r;
        bool ok = arow < M;
        const unsigned short* ap = A + (size_t)(ok ? arow : 0) * K;
        #pragma unroll
        for (int kk = 0; kk < KK; kk++) {
            short8 v = *(const short8*)(ap + kk * 32 + q * 8);
            if (!ok) v = (short8){0, 0, 0, 0, 0, 0, 0, 0};
            a[mi][kk] = v;
        }
    }

    for (int t = 0; t < ntiles; t++) {
        int n0 = nbase + t * 64;
        if (t > 0) __syncthreads();
        #pragma unroll
        for (int pass = 0; pass < 64 * CPR / 256; pass++) {
            int f = pass * 256 + tid;
            int row = f / CPR, ch = f % CPR;
            *(short8*)&Bs[row * S + ch * 8] =
                *(const short8*)(Bt + (size_t)(n0 + row) * K + ch * 8);
        }
        __syncthreads();

        f32x4 acc[2][4];
        #pragma unroll
        for (int mi = 0; mi < 2; mi++)
            #pragma unroll
            for (int j = 0; j < 4; j++) acc[mi][j] = (f32x4){0.f, 0.f, 0.f, 0.f};

        #pragma unroll
        for (int kk = 0; kk < KK; kk++) {
            short8 b[4];
            #pragma unroll
            for (int j = 0; j < 4; j++)
                b[j] = *(short8*)&Bs[(j * 16 + r) * S + kk * 32 + q * 8];
            #pragma unroll
            for (int mi = 0; mi < 2; mi++)
                #pragma unroll
                for (int j = 0; j < 4; j++)
                    acc[mi][j] = __builtin_amdgcn_mfma_f32_16x16x32_bf16(a[mi][kk], b[j], acc[mi][j], 0, 0, 0);
        }

        __syncthreads();
        #pragma unroll
        for (int mi = 0; mi < 2; mi++)
            #pragma unroll
            for (int j = 0; j < 4; j++)
                #pragma unroll
                for (int p = 0; p < 4; p++)
                    Cs[(wave * 32 + mi * 16 + q * 4 + p) * CS + j * 16 + r] = acc[mi][j][p];
        __syncthreads();

        int row = tid >> 1;
        int halfc = (tid & 1) * 32;
        int grow = blockIdx.y * 128 + row;
        if (grow < M) {
            float vals[32];
            #pragma unroll
            for (int c = 0; c < 8; c++)
                *(f32x4*)&vals[c * 4] = *(f32x4*)&Cs[row * CS + halfc + c * 4];
            float di = 1.f, rdi = 1.f;
            if (SCALE) { di = dinv[grow]; if (RES) rdi = 1.f / di; }
            float bb[32];
            #pragma unroll
            for (int c = 0; c < 8; c++)
                *(f32x4*)&bb[c * 4] = *(const f32x4*)&bias[n0 + halfc + c * 4];
            short8 rv[4];
            if (RES) {
                #pragma unroll
                for (int c = 0; c < 4; c++)
                    rv[c] = *(const short8*)(residual + (size_t)grow * N + n0 + halfc + c * 8);
            }
            #pragma unroll
            for (int c = 0; c < 32; c++) {
                float v = (SCALE ? di * vals[c] : vals[c]) + bb[c];
                if (RELU) v = fmaxf(v, 0.f);
                if (RES) v += bf2f((unsigned short)rv[c / 8][c % 8]) * rdi;
                if (SCALE == 1) v *= di;
                vals[c] = v;
            }
            if (OUTF32) {
                float* cp = (float*)Cout + (size_t)grow * N + n0 + halfc;
                #pragma unroll
                for (int c = 0; c < 8; c++) *(f32x4*)&cp[c * 4] = *(f32x4*)&vals[c * 4];
            } else {
                unsigned short* cp = (unsigned short*)Cout + (size_t)grow * N + n0 + halfc;
                #pragma unroll
                for (int c = 0; c < 4; c++) {
                    short8 o;
                    #pragma unroll
                    for (int u = 0; u < 8; u++) o[u] = (short)f2bf(vals[c * 8 + u]);
                    *(short8*)&cp[c * 8] = o;
                }
            }
            if (FP8O) {
                unsigned int w[8];
                #pragma unroll
                for (int c = 0; c < 8; c++) {
                    unsigned int p = 0;
                    p = __builtin_amdgcn_cvt_pk_fp8_f32(vals[c * 4 + 0], vals[c * 4 + 1], p, false);
                    p = __builtin_amdgcn_cvt_pk_fp8_f32(vals[c * 4 + 2], vals[c * 4 + 3], p, true);
                    w[c] = p;
                }
                unsigned char* fp = f8out + (size_t)grow * N + n0 + halfc;
                *(uint4*)(fp) = make_uint4(w[0], w[1], w[2], w[3]);
                *(uint4*)(fp + 16) = make_uint4(w[4], w[5], w[6], w[7]);
            }
        }
    }
}

// ---------------------------- pool / LN ------------------------------------

__launch_bounds__(256)
__global__ void pool_kernel(const unsigned short* __restrict__ h, const int* __restrict__ batch,
                            unsigned short* __restrict__ g0, int n, int G) {
    int g = blockIdx.x * 4 + (threadIdx.x >> 6);
    int lane = threadIdx.x & 63;
    if (g >= G) return;
    int lo = 0, hi = 0;
    if (lane == 0) {
        int a = 0, b = n;
        while (a < b) { int m = (a + b) >> 1; if (batch[m] < g) a = m + 1; else b = m; }
        lo = a;
        int a2 = a, b2 = n;
        while (a2 < b2) { int m = (a2 + b2) >> 1; if (batch[m] < g + 1) a2 = m + 1; else b2 = m; }
        hi = a2;
    }
    lo = __shfl(lo, 0); hi = __shfl(hi, 0);
    float a0 = 0.f, a1 = 0.f, a2 = 0.f, a3 = 0.f;
    for (int i = lo; i < hi; i++) {
        ushort4 v = *(const ushort4*)(h + (size_t)i * 256 + lane * 4);
        a0 += bf2f(v.x); a1 += bf2f(v.y); a2 += bf2f(v.z); a3 += bf2f(v.w);
    }
    float inv = 1.0f / fmaxf((float)(hi - lo), 1.0f);
    ushort4 o;
    o.x = f2bf(a0 * inv); o.y = f2bf(a1 * inv); o.z = f2bf(a2 * inv); o.w = f2bf(a3 * inv);
    *(ushort4*)(g0 + (size_t)g * 256 + lane * 4) = o;
}

__launch_bounds__(256)
__global__ void ln_kernel(const float* __restrict__ g2, const float* __restrict__ gamma,
                          const float* __restrict__ beta, float* __restrict__ out, int rows) {
    int row = blockIdx.x * 4 + (threadIdx.x >> 6);
    int lane = threadIdx.x & 63;
    if (row >= rows) return;
    const float* r = g2 + (size_t)row * 768;
    float v[12];
    float s = 0.f, s2 = 0.f;
    #pragma unroll
    for (int j = 0; j < 12; j++) {
        v[j] = r[lane + 64 * j];
        s += v[j];
        s2 += v[j] * v[j];
    }
    #pragma unroll
    for (int off = 32; off > 0; off >>= 1) {
        s += __shfl_down(s, off);
        s2 += __shfl_down(s2, off);
    }
    s = __shfl(s, 0);
    s2 = __shfl(s2, 0);
    float mu = s * (1.0f / 768.0f);
    float var = s2 * (1.0f / 768.0f) - mu * mu;
    float inv = rsqrtf(var + 1e-5f);
    #pragma unroll
    for (int j = 0; j < 12; j++) {
        int c = lane + 64 * j;
        out[(size_t)row * 768 + c] = (v[j] - mu) * inv * gamma[c] + beta[c];
    }
}

// ---------------------------------------------------------------------------

extern "C" void kernel_launch(void* const* d_in, const int* in_sizes, int n_in,
                              void* d_out, int out_size, void* d_ws, size_t ws_size,
                              hipStream_t stream) {
    const float* x    = (const float*)d_in[0];
    const int* eidx   = (const int*)d_in[1];
    const int* batch  = (const int*)d_in[2];
    const float* W1   = (const float*)d_in[3];
    const float* b1   = (const float*)d_in[4];
    const float* W2   = (const float*)d_in[5];
    const float* b2   = (const float*)d_in[6];
    const float* W3   = (const float*)d_in[7];
    const float* b3   = (const float*)d_in[8];
    const float* P1   = (const float*)d_in[9];
    const float* pb1  = (const float*)d_in[10];
    const float* P2   = (const float*)d_in[11];
    const float* pb2  = (const float*)d_in[12];
    const float* ln_g = (const float*)d_in[13];
    const float* ln_b = (const float*)d_in[14];
    float* out = (float*)d_out;

    const int N = in_sizes[2];            // 50000
    const int E = in_sizes[1] / 2;        // 800000
    const int F_IN = in_sizes[0] / N;     // 128
    const int H = in_sizes[4];            // 256
    const int D = in_sizes[12];           // 768
    const int G = out_size / D;           // 1024
    const int NPAD = (N + 127) & ~127;
    const int NB = (N + 511) / 512;       // scan blocks (<=128)

    const int* src = eidx;
    const int* dst = eidx + E;

    char* ws = (char*)d_ws;
    size_t off = 0;
    auto alloc = [&](size_t bytes) -> char* {
        char* p = ws + off;
        off = (off + bytes + 255) & ~(size_t)255;
        return p;
    };
    int*   cnt      = (int*)alloc((size_t)NPAD * 4);
    float* dinv     = (float*)alloc((size_t)NPAD * 4);
    int*   row_ptr  = (int*)alloc((size_t)(N + 1) * 4);
    int*   bsum     = (int*)alloc(128 * 4);
    int*   rank     = (int*)alloc((size_t)E * 4);
    int*   csr      = (int*)alloc((size_t)E * 4);
    unsigned char* xf8  = (unsigned char*)alloc((size_t)(N + 1) * F_IN);      // x̂ fp8, +dummy
    unsigned char* h1f8 = (unsigned char*)alloc((size_t)(N + 1) * H);         // ĥ1 fp8, +dummy
    unsigned char* h2f8 = (unsigned char*)alloc((size_t)(N + 1) * H);         // ĥ2 fp8, +dummy
    unsigned short* Wt1 = (unsigned short*)alloc((size_t)F_IN * H * 2);
    unsigned short* Wt2 = (unsigned short*)alloc((size_t)H * H * 2);
    unsigned short* Wt3 = (unsigned short*)alloc((size_t)H * H * 2);
    unsigned short* Pt1 = (unsigned short*)alloc((size_t)H * H * 2);
    unsigned short* Pt2 = (unsigned short*)alloc((size_t)H * D * 2);
    unsigned short* t1  = (unsigned short*)alloc((size_t)N * F_IN * 2);       // Σ x̂ (bf16)
    unsigned short* tA  = (unsigned short*)alloc((size_t)N * H * 2);          // Σ ĥ (bf16)
    unsigned short* hh1 = (unsigned short*)alloc((size_t)N * H * 2);          // ĥ1 bf16 (residual)
    unsigned short* hh2 = (unsigned short*)alloc((size_t)N * H * 2);          // ĥ2 bf16 (residual)
    unsigned short* h3  = (unsigned short*)alloc((size_t)N * H * 2);
    unsigned short* g0b = (unsigned short*)alloc((size_t)G * H * 2);
    unsigned short* g1b = (unsigned short*)alloc((size_t)G * H * 2);
    float* g2 = (float*)alloc((size_t)G * D * 4);
    (void)ws_size; (void)n_in;

    // --- CSR build -----------------------------------------------------------
    hipMemsetAsync(cnt, 0, (size_t)NPAD * 4, stream);
    count_kernel<<<(E + 255) / 256, 256, 0, stream>>>(dst, E, cnt, rank);
    scanA<<<NB, 512, 0, stream>>>(cnt, N, bsum, dinv);
    scanC<<<NB, 512, 0, stream>>>(cnt, N, bsum, E, row_ptr);

    // --- fused scatter + conversions (one launch) ---------------------------
    {
        int n4 = N * F_IN / 4;
        int tot = F_IN * H + 3 * H * H + H * D;
        int total = E + n4 + tot + 640;
        convert_all<<<(total + 255) / 256, 256, 0, stream>>>(
            src, dst, row_ptr, rank, csr, E,
            x, dinv, xf8, n4, W1, W2, W3, P1, P2, Wt1, Wt2, Wt3, Pt1, Pt2, F_IN, H, D,
            xf8 + (size_t)N * F_IN, h1f8 + (size_t)N * H, h2f8 + (size_t)N * H);
    }

    // --- GCN layers (aggregate-first, ĥ-space, fp8 gathers) -----------------
    int agg_grid = (N + 3) / 4;
    int mtiles = (N + 127) / 128;

    // layer 1: t1 = x̂[i] + Σ x̂[src]; ĥ1 = di*relu(di*(t1 W1) + b1)  (+fp8)
    aggregate128<<<agg_grid, 256, 0, stream>>>(xf8, row_ptr, csr, t1, N, N);
    wgemm<128, 1, 0, 0, 1, 1><<<dim3(4, mtiles), 256, 0, stream>>>(t1, Wt1, b1, nullptr, dinv, hh1, h1f8, N, H, 1);

    // layer 2: t2 = ĥ1[i] + Σ ĥ1[src]; ĥ2 = di*(relu(di*(t2 W2)+b2) + ĥ1/di)
    aggregate256<<<agg_grid, 256, 0, stream>>>(h1f8, row_ptr, csr, tA, N, N);
    wgemm<256, 1, 1, 0, 1, 1><<<dim3(4, mtiles), 256, 0, stream>>>(tA, Wt2, b2, hh1, dinv, hh2, h2f8, N, H, 1);

    // layer 3: t3 = ĥ2[i] + Σ ĥ2[src]; h3 = relu(di*(t3 W3)+b3) + ĥ2/di
    aggregate256<<<agg_grid, 256, 0, stream>>>(h2f8, row_ptr, csr, tA, N, N);
    wgemm<256, 1, 1, 0, 2, 0><<<dim3(4, mtiles), 256, 0, stream>>>(tA, Wt3, b3, hh2, dinv, h3, nullptr, N, H, 1);

    // --- pool + MLP + LN -----------------------------------------------------
    pool_kernel<<<(G + 3) / 4, 256, 0, stream>>>(h3, batch, g0b, N, G);
    wgemm<256, 1, 0, 0, 0, 0><<<dim3(4, G / 128), 256, 0, stream>>>(g0b, Pt1, pb1, nullptr, nullptr, g1b, nullptr, G, H, 1);
    wgemm<256, 0, 0, 1, 0, 0><<<dim3(12, G / 128), 256, 0, stream>>>(g1b, Pt2, pb2, nullptr, nullptr, g2, nullptr, G, D, 1);
    ln_kernel<<<G / 4, 256, 0, stream>>>(g2, ln_g, ln_b, out, G);
}